// Round 5
// baseline (349.462 us; speedup 1.0000x reference)
//
#include <hip/hip_runtime.h>

#define BB   8
#define CC   64
#define HWN  19200
#define NPTS 12800
#define NSUB 3200
#define KNN  16
#define OUTN (HWN + NSUB)   // 22400

#define GRID_BLOCKS 1280
#define NGRP  8                         // groups == batches == XCDs (bid & 7)
#define GBLK  (GRID_BLOCKS / NGRP)      // 160 blocks per group

typedef __attribute__((ext_vector_type(8))) short short8;
typedef __attribute__((ext_vector_type(4))) float floatx4;

__device__ __forceinline__ unsigned short f2bf(float f) {
    union { float f; unsigned int i; } v; v.f = f;
    unsigned int r = v.i + 0x7fffu + ((v.i >> 16) & 1u);
    return (unsigned short)(r >> 16);
}
__device__ __forceinline__ float bf2f(unsigned short u) {
    union { unsigned int i; float f; } v; v.i = ((unsigned int)u) << 16; return v.f;
}

struct P {
    const float* pfeat; const float* rgb;
    const float* w0; const float* w1; const float* w2; const float* w3;
    const float* s_pp; const float* b_pp;
    const float* s_rp; const float* b_rp;
    const float* s_pf; const float* b_pf;
    const float* s_rf; const float* b_rf;
    const int* pool_idx; const int* p2r_idx; const int* r2p_idx;
    ushort* wB; ushort* pfT; ushort* rgbT;
    ushort* pe0T; ushort* p2rT; ushort* r2pT;
    unsigned* bar;
    float* out;
};

// Per-group (160-block) barrier, flag-array + generation broadcast.
// Layout in p.bar: gen[g] at bar[g*16]; flag[g][lj] at bar[128+(g*GBLK+lj)*16]
// (64B spacing -> no line sharing). Arrival = one plain device-scope store per
// block (parallel; same-address RMW serialized ~200ns x N in R2).
// Co-residency: capacity 6 blocks/CU (launch_bounds) = 1536 slots; we launch
// only 1280 -> 256 slack slots, so residency (and barrier liveness) is robust
// to dispatch imbalance. R4's zero-margin 1536/1536 fit is the suspected hang.
__device__ __forceinline__ void gbar(unsigned* bar, int g, int lj, unsigned phase) {
    __syncthreads();
    unsigned* genp = bar + g * 16;
    unsigned* flg  = bar + 128 + (g * GBLK) * 16;
    int tid = threadIdx.x;
    if (lj == 0) {
        for (int j = 1 + tid; j < GBLK; j += 256)
            while (__hip_atomic_load(flg + j * 16, __ATOMIC_RELAXED, __HIP_MEMORY_SCOPE_AGENT) < phase)
                __builtin_amdgcn_s_sleep(2);
        __syncthreads();
        if (tid == 0) {
            __threadfence();   // flush own stores + invalidate stale lines
            __hip_atomic_store(genp, phase, __ATOMIC_RELEASE, __HIP_MEMORY_SCOPE_AGENT);
        }
        __syncthreads();
    } else {
        if (tid == 0) {
            __threadfence();   // publish this block's phase stores
            __hip_atomic_store(flg + lj * 16, phase, __ATOMIC_RELAXED, __HIP_MEMORY_SCOPE_AGENT);
            while (__hip_atomic_load(genp, __ATOMIC_RELAXED, __HIP_MEMORY_SCOPE_AGENT) < phase)
                __builtin_amdgcn_s_sleep(8);
            __threadfence();   // invalidate stale lines before reading remote data
        }
        __syncthreads();
    }
}

// ---------------------------------------------------------------------------
// Fused kernel, per-batch groups: group g (= bid&7 = batch = XCD) runs
// phase1 (transpose 250 vb + weights 6 vb), gbar, phase2 (100 vb), gbar,
// phase3 (88 vb) for batch g only. Phase bodies identical to R3; this round
// changes ONLY occupancy: 2 -> ~5 blocks/CU (grid 512 -> 1280, margin vs R4).
// ---------------------------------------------------------------------------
__global__ __launch_bounds__(256, 6) void k_all(P p) {
    __shared__ alignas(16) ushort sm[2][64 * 65];   // 16640 B; phase2 reuses as [64*72]
    int tid = threadIdx.x;
    int bid = blockIdx.x;
    int g   = bid & 7;      // batch / group / XCD
    int lj  = bid >> 3;     // 0..159 local block id
    ushort* wBg = p.wB + (size_t)g * 24576;

    // ---- PHASE 1: transpose f32 [C][N] -> bf16 [N][C] for batch g + weights
    for (int vb = lj; vb < 256; vb += GBLK) {
        if (vb >= 250) {
            // weight slice (vb-250) in [0,6): 4096 elems, 16/thread, region-uniform
            int i0 = (vb - 250) * 4096 + tid * 16;
            const float* wsrc; int roff;
            if (i0 < 4096)       { wsrc = p.w0; roff = i0; }
            else if (i0 < 8192)  { wsrc = p.w1; roff = i0 - 4096; }
            else if (i0 < 16384) { wsrc = p.w2; roff = i0 - 8192; }
            else                 { wsrc = p.w3; roff = i0 - 16384; }
            #pragma unroll
            for (int q = 0; q < 16; q += 4) {
                float4 v = *(const float4*)(wsrc + roff + q);
                ushort4 r;
                r.x = f2bf(v.x); r.y = f2bf(v.y); r.z = f2bf(v.z); r.w = f2bf(v.w);
                *(ushort4*)(wBg + i0 + q) = r;
            }
        } else {
            bool isR = (vb >= 100);
            int xx = isR ? vb - 100 : vb;
            const float* src = (isR ? p.rgb : p.pfeat);
            ushort* outp     = (isR ? p.rgbT : p.pfT);
            int N  = isR ? HWN : NPTS;
            int n0 = xx * 128;
            src += (size_t)g * CC * N + n0;

            int l = tid & 15, ch = tid >> 4;
            float4 v[2][4];
            #pragma unroll
            for (int s = 0; s < 2; ++s)
                #pragma unroll
                for (int it = 0; it < 4; ++it)
                    v[s][it] = *(const float4*)(src + (size_t)(ch + 16 * it) * N + s * 64 + 4 * l);
            #pragma unroll
            for (int s = 0; s < 2; ++s)
                #pragma unroll
                for (int it = 0; it < 4; ++it) {
                    int c = ch + 16 * it;
                    sm[s][c * 65 + 4 * l + 0] = f2bf(v[s][it].x);
                    sm[s][c * 65 + 4 * l + 1] = f2bf(v[s][it].y);
                    sm[s][c * 65 + 4 * l + 2] = f2bf(v[s][it].z);
                    sm[s][c * 65 + 4 * l + 3] = f2bf(v[s][it].w);
                }
            __syncthreads();
            ushort* dst = outp + ((size_t)g * N + n0) * CC;
            int c8 = (tid & 7) * 8;
            #pragma unroll
            for (int pass = 0; pass < 4; ++pass) {
                int n_loc = (tid >> 3) + 32 * pass;
                int s = n_loc >> 6, n = n_loc & 63;
                short8 r;
                #pragma unroll
                for (int u = 0; u < 8; ++u)
                    r[u] = (short)sm[s][(c8 + u) * 65 + n];
                *(short8*)(dst + (size_t)n_loc * CC + c8) = r;
            }
        }
        __syncthreads();   // protect sm reuse across grid-stride iterations
    }
    gbar(p.bar, g, lj, 1u);

    // ---- PHASE 2: gather + maxpool + pre-conv GEMM (batch g), 100 vblocks --
    ushort* sg = &sm[0][0];   // reused as [64*72]
    for (int vb = lj; vb < 100; vb += GBLK) {
        bool pt = (vb < 50);
        int xx = pt ? vb : vb - 50;
        int m0 = xx * 64;
        const ushort* xT  = pt ? p.pfT : p.rgbT;
        const int*    idx = pt ? p.pool_idx : p.r2p_idx;
        int Nin           = pt ? NPTS : HWN;
        const ushort* W   = pt ? wBg : wBg + 4096;   // [64][64]
        const float*  sv  = pt ? p.s_pp : p.s_rp;
        const float*  bv  = pt ? p.b_pp : p.b_rp;
        ushort*       dst = pt ? p.p2rT : p.r2pT;

        int c8   = (tid & 7) * 8;
        int mloc = tid >> 3;          // 0..31: 32 points per pass
        const ushort* xb = xT + (size_t)g * Nin * CC + c8;
        #pragma unroll
        for (int pass = 0; pass < 2; ++pass) {
            int ml = mloc + pass * 32;
            int m  = m0 + ml;
            const int4* ip4 = (const int4*)(idx + ((size_t)g * NSUB + m) * KNN);
            int4 q0 = ip4[0], q1 = ip4[1], q2 = ip4[2], q3 = ip4[3];
            int js[16] = { q0.x, q0.y, q0.z, q0.w, q1.x, q1.y, q1.z, q1.w,
                           q2.x, q2.y, q2.z, q2.w, q3.x, q3.y, q3.z, q3.w };
            float a[8];
            #pragma unroll
            for (int u = 0; u < 8; ++u) a[u] = -1e30f;
            #pragma unroll
            for (int k = 0; k < KNN; ++k) {
                short8 val = *(const short8*)(xb + (size_t)js[k] * CC);
                #pragma unroll
                for (int u = 0; u < 8; ++u)
                    a[u] = fmaxf(a[u], bf2f((unsigned short)val[u]));
            }
            short8 r;
            #pragma unroll
            for (int u = 0; u < 8; ++u) r[u] = (short)f2bf(a[u]);
            *(short8*)(&sg[ml * 72 + c8]) = r;
            if (pt)
                *(short8*)(p.pe0T + ((size_t)g * NSUB + m) * CC + c8) = r;
        }
        __syncthreads();
        int wave = tid >> 6, lane = tid & 63;
        int l15 = lane & 15, quad = lane >> 4;
        int nloc0 = wave * 16;
        floatx4 acc[4] = {{0.f,0.f,0.f,0.f},{0.f,0.f,0.f,0.f},{0.f,0.f,0.f,0.f},{0.f,0.f,0.f,0.f}};
        #pragma unroll
        for (int kk = 0; kk < 2; ++kk) {
            short8 a = *(const short8*)(&sg[(nloc0 + l15) * 72 + kk * 32 + quad * 8]);
            #pragma unroll
            for (int t = 0; t < 4; ++t) {
                short8 wf = *(const short8*)(W + (size_t)(t * 16 + l15) * CC + kk * 32 + quad * 8);
                acc[t] = __builtin_amdgcn_mfma_f32_16x16x32_bf16(a, wf, acc[t], 0, 0, 0);
            }
        }
        #pragma unroll
        for (int t = 0; t < 4; ++t) {
            int o = t * 16 + l15;
            float ss = sv[o], bb2 = bv[o];
            #pragma unroll
            for (int r = 0; r < 4; ++r) {
                int n = m0 + nloc0 + quad * 4 + r;
                float y = fmaxf(acc[t][r] * ss + bb2, 0.f);
                dst[((size_t)g * NSUB + n) * CC + o] = f2bf(y);
            }
        }
        __syncthreads();   // protect sg reuse across grid-stride iterations
    }
    gbar(p.bar, g, lj, 2u);

    // ---- PHASE 3: both fuse GEMMs -> d_out (batch g), 88 vblocks -----------
    for (int vb = lj; vb < 88; vb += GBLK) {
        bool rp = (vb < 75);
        int x0 = rp ? vb : vb - 75;       // rgb 0..74 / pt 0..12
        const ushort* x1T = rp ? p.rgbT : p.pe0T;
        const ushort* x2T = rp ? p.p2rT : p.r2pT;
        int N             = rp ? HWN : NSUB;
        int pos0          = rp ? 0 : HWN;
        const ushort* W   = rp ? wBg + 8192 : wBg + 16384;   // [64][128]
        const float*  sv  = rp ? p.s_pf : p.s_rf;
        const float*  bv  = rp ? p.b_pf : p.b_rf;

        int wave = tid >> 6, lane = tid & 63;
        int l15 = lane & 15, quad = lane >> 4;
        int n_base = x0 * 256 + wave * 64;
        int ncol   = n_base + l15 * 4;
        bool act   = rp || (ncol < NSUB);
        int nc     = act ? ncol : 0;

        // preload all B-fragments: xf[kk][gg], 16 independent 16B loads
        short8 xf[4][4];
        {
            const ushort* r1[4];
            const ushort* r2[4];
            if (rp) {
                int4 i4 = *(const int4*)(p.p2r_idx + (size_t)g * N + nc);
                int n2s[4] = { i4.x, i4.y, i4.z, i4.w };
                #pragma unroll
                for (int gg = 0; gg < 4; ++gg) {
                    r1[gg] = x1T + ((size_t)g * N + nc + gg) * CC + quad * 8;
                    r2[gg] = x2T + ((size_t)g * NSUB + n2s[gg]) * CC + quad * 8;
                }
            } else {
                #pragma unroll
                for (int gg = 0; gg < 4; ++gg) {
                    r1[gg] = x1T + ((size_t)g * N + nc + gg) * CC + quad * 8;
                    r2[gg] = x2T + ((size_t)g * NSUB + nc + gg) * CC + quad * 8;
                }
            }
            #pragma unroll
            for (int gg = 0; gg < 4; ++gg) {
                xf[0][gg] = *(const short8*)(r1[gg]);
                xf[1][gg] = *(const short8*)(r1[gg] + 32);
                xf[2][gg] = *(const short8*)(r2[gg]);
                xf[3][gg] = *(const short8*)(r2[gg] + 32);
            }
        }

        float* outb = p.out + (size_t)g * CC * OUTN + pos0 + nc;
        #pragma unroll
        for (int t = 0; t < 4; ++t) {
            floatx4 acc[4] = {{0.f,0.f,0.f,0.f},{0.f,0.f,0.f,0.f},
                              {0.f,0.f,0.f,0.f},{0.f,0.f,0.f,0.f}};
            #pragma unroll
            for (int kk = 0; kk < 4; ++kk) {
                short8 wf = *(const short8*)(W + (size_t)(t * 16 + l15) * 128 + kk * 32 + quad * 8);
                #pragma unroll
                for (int gg = 0; gg < 4; ++gg)
                    acc[gg] = __builtin_amdgcn_mfma_f32_16x16x32_bf16(wf, xf[kk][gg], acc[gg], 0, 0, 0);
            }
            // store tile t immediately: overlaps next tile's MFMA
            #pragma unroll
            for (int r = 0; r < 4; ++r) {
                int o = t * 16 + quad * 4 + r;
                float ss = sv[o], bb2 = bv[o];
                floatx4 y;
                y[0] = fmaxf(acc[0][r] * ss + bb2, 0.f);
                y[1] = fmaxf(acc[1][r] * ss + bb2, 0.f);
                y[2] = fmaxf(acc[2][r] * ss + bb2, 0.f);
                y[3] = fmaxf(acc[3][r] * ss + bb2, 0.f);
                if (act)
                    __builtin_nontemporal_store(y, (floatx4*)(outb + (size_t)o * OUTN));
            }
        }
    }
}

extern "C" void kernel_launch(void* const* d_in, const int* in_sizes, int n_in,
                              void* d_out, int out_size, void* d_ws, size_t ws_size,
                              hipStream_t stream) {
    char* ws = (char*)d_ws;
    ushort* wB   = (ushort*)ws; ws += (size_t)NGRP * 24576 * 2;   // 8 group copies
    ushort* pfT  = (ushort*)ws; ws += (size_t)BB * NPTS * CC * 2;
    ushort* rgbT = (ushort*)ws; ws += (size_t)BB * HWN  * CC * 2;
    ushort* pe0T = (ushort*)ws; ws += (size_t)BB * NSUB * CC * 2;
    ushort* p2rT = (ushort*)ws; ws += (size_t)BB * NSUB * CC * 2;
    ushort* r2pT = (ushort*)ws; ws += (size_t)BB * NSUB * CC * 2;
    unsigned* bar = (unsigned*)ws; ws += 131072;

    // re-arm barriers every iteration (workspace is poisoned between runs):
    // gens 512B + 1280 flags * 64B = 82432B -> memset that much
    hipMemsetAsync(bar, 0, 82432, stream);

    P p;
    p.pfeat = (const float*)d_in[1];
    p.rgb   = (const float*)d_in[0];
    p.w0    = (const float*)d_in[2];
    p.w1    = (const float*)d_in[8];
    p.w2    = (const float*)d_in[5];
    p.w3    = (const float*)d_in[11];
    p.s_pp  = (const float*)d_in[3];   p.b_pp = (const float*)d_in[4];
    p.s_rp  = (const float*)d_in[9];   p.b_rp = (const float*)d_in[10];
    p.s_pf  = (const float*)d_in[6];   p.b_pf = (const float*)d_in[7];
    p.s_rf  = (const float*)d_in[12];  p.b_rf = (const float*)d_in[13];
    p.pool_idx = (const int*)d_in[14];
    p.p2r_idx  = (const int*)d_in[15];
    p.r2p_idx  = (const int*)d_in[16];
    p.wB = wB; p.pfT = pfT; p.rgbT = rgbT;
    p.pe0T = pe0T; p.p2rT = p2rT; p.r2pT = r2pT;
    p.bar = bar;
    p.out = (float*)d_out;

    k_all<<<dim3(GRID_BLOCKS), 256, 0, stream>>>(p);
}

// Round 8
// 298.021 us; speedup vs baseline: 1.1726x; 1.1726x over previous
//
#include <hip/hip_runtime.h>

#define BB   8
#define CC   64
#define HWN  19200
#define NPTS 12800
#define NSUB 3200
#define KNN  16
#define OUTN (HWN + NSUB)   // 22400

#define GRID_BLOCKS 960
#define NGRP  8                         // groups == batches == XCDs (bid & 7)
#define GBLK  (GRID_BLOCKS / NGRP)      // 120 blocks per group

typedef __attribute__((ext_vector_type(8))) short short8;
typedef __attribute__((ext_vector_type(4))) float floatx4;

__device__ __forceinline__ unsigned short f2bf(float f) {
    union { float f; unsigned int i; } v; v.f = f;
    unsigned int r = v.i + 0x7fffu + ((v.i >> 16) & 1u);
    return (unsigned short)(r >> 16);
}
__device__ __forceinline__ float bf2f(unsigned short u) {
    union { unsigned int i; float f; } v; v.i = ((unsigned int)u) << 16; return v.f;
}

struct P {
    const float* pfeat; const float* rgb;
    const float* w0; const float* w1; const float* w2; const float* w3;
    const float* s_pp; const float* b_pp;
    const float* s_rp; const float* b_rp;
    const float* s_pf; const float* b_pf;
    const float* s_rf; const float* b_rf;
    const int* pool_idx; const int* p2r_idx; const int* r2p_idx;
    ushort* wB; ushort* pfT; ushort* rgbT;
    ushort* pe0T; ushort* p2rT; ushort* r2pT;
    unsigned* bar;
    float* out;
};

// Per-group (120-block) barrier, flag-array + generation broadcast.
// OCCUPANCY BIN LAW (m69, session-verified): waves/CU halve at VGPR 64/128/256
// => at VGPR=72 (natural, launch_bounds(256,4) budget 128, no spill) capacity
// is 4 blocks/CU = 1024 slots. R6/R7 hang: 1280 blocks > 1024 slots -> 256
// blocks never resident -> spin-barrier deadlock. Grid 960 leaves 64 slack
// slots under the bin law (1792-slot fine-granularity law: huge slack).
// R5 lesson: (256,6) squeezed VGPR 72->40 => scratch spills, +65MB HBM, 2x slow.
__device__ __forceinline__ void gbar(unsigned* bar, int g, int lj, unsigned phase) {
    __syncthreads();
    unsigned* genp = bar + g * 16;
    unsigned* flg  = bar + 128 + (g * GBLK) * 16;
    int tid = threadIdx.x;
    if (lj == 0) {
        for (int j = 1 + tid; j < GBLK; j += 256)
            while (__hip_atomic_load(flg + j * 16, __ATOMIC_RELAXED, __HIP_MEMORY_SCOPE_AGENT) < phase)
                __builtin_amdgcn_s_sleep(2);
        __syncthreads();
        if (tid == 0) {
            __threadfence();   // flush own stores + invalidate stale lines
            __hip_atomic_store(genp, phase, __ATOMIC_RELEASE, __HIP_MEMORY_SCOPE_AGENT);
        }
        __syncthreads();
    } else {
        if (tid == 0) {
            __threadfence();   // publish this block's phase stores
            __hip_atomic_store(flg + lj * 16, phase, __ATOMIC_RELAXED, __HIP_MEMORY_SCOPE_AGENT);
            while (__hip_atomic_load(genp, __ATOMIC_RELAXED, __HIP_MEMORY_SCOPE_AGENT) < phase)
                __builtin_amdgcn_s_sleep(8);
            __threadfence();   // invalidate stale lines before reading remote data
        }
        __syncthreads();
    }
}

// ---------------------------------------------------------------------------
// Fused kernel, per-batch groups: group g (= bid&7 = batch = XCD) runs
// phase1 (transpose 250 vb + weights 6 vb), gbar, phase2 (100 vb), gbar,
// phase3 (88 vb) for batch g only. Phase bodies identical to R3/R5.
// This round: grid 1280 -> 960 to fit the 4-blocks/CU bin at VGPR=72.
// ---------------------------------------------------------------------------
__global__ __launch_bounds__(256, 4) void k_all(P p) {
    __shared__ alignas(16) ushort sm[2][64 * 65];   // 16640 B; phase2 reuses as [64*72]
    int tid = threadIdx.x;
    int bid = blockIdx.x;
    int g   = bid & 7;      // batch / group / XCD
    int lj  = bid >> 3;     // 0..119 local block id
    ushort* wBg = p.wB + (size_t)g * 24576;

    // ---- PHASE 1: transpose f32 [C][N] -> bf16 [N][C] for batch g + weights
    for (int vb = lj; vb < 256; vb += GBLK) {
        if (vb >= 250) {
            // weight slice (vb-250) in [0,6): 4096 elems, 16/thread, region-uniform
            int i0 = (vb - 250) * 4096 + tid * 16;
            const float* wsrc; int roff;
            if (i0 < 4096)       { wsrc = p.w0; roff = i0; }
            else if (i0 < 8192)  { wsrc = p.w1; roff = i0 - 4096; }
            else if (i0 < 16384) { wsrc = p.w2; roff = i0 - 8192; }
            else                 { wsrc = p.w3; roff = i0 - 16384; }
            #pragma unroll
            for (int q = 0; q < 16; q += 4) {
                float4 v = *(const float4*)(wsrc + roff + q);
                ushort4 r;
                r.x = f2bf(v.x); r.y = f2bf(v.y); r.z = f2bf(v.z); r.w = f2bf(v.w);
                *(ushort4*)(wBg + i0 + q) = r;
            }
        } else {
            bool isR = (vb >= 100);
            int xx = isR ? vb - 100 : vb;
            const float* src = (isR ? p.rgb : p.pfeat);
            ushort* outp     = (isR ? p.rgbT : p.pfT);
            int N  = isR ? HWN : NPTS;
            int n0 = xx * 128;
            src += (size_t)g * CC * N + n0;

            int l = tid & 15, ch = tid >> 4;
            float4 v[2][4];
            #pragma unroll
            for (int s = 0; s < 2; ++s)
                #pragma unroll
                for (int it = 0; it < 4; ++it)
                    v[s][it] = *(const float4*)(src + (size_t)(ch + 16 * it) * N + s * 64 + 4 * l);
            #pragma unroll
            for (int s = 0; s < 2; ++s)
                #pragma unroll
                for (int it = 0; it < 4; ++it) {
                    int c = ch + 16 * it;
                    sm[s][c * 65 + 4 * l + 0] = f2bf(v[s][it].x);
                    sm[s][c * 65 + 4 * l + 1] = f2bf(v[s][it].y);
                    sm[s][c * 65 + 4 * l + 2] = f2bf(v[s][it].z);
                    sm[s][c * 65 + 4 * l + 3] = f2bf(v[s][it].w);
                }
            __syncthreads();
            ushort* dst = outp + ((size_t)g * N + n0) * CC;
            int c8 = (tid & 7) * 8;
            #pragma unroll
            for (int pass = 0; pass < 4; ++pass) {
                int n_loc = (tid >> 3) + 32 * pass;
                int s = n_loc >> 6, n = n_loc & 63;
                short8 r;
                #pragma unroll
                for (int u = 0; u < 8; ++u)
                    r[u] = (short)sm[s][(c8 + u) * 65 + n];
                *(short8*)(dst + (size_t)n_loc * CC + c8) = r;
            }
        }
        __syncthreads();   // protect sm reuse across grid-stride iterations
    }
    gbar(p.bar, g, lj, 1u);

    // ---- PHASE 2: gather + maxpool + pre-conv GEMM (batch g), 100 vblocks --
    ushort* sg = &sm[0][0];   // reused as [64*72]
    for (int vb = lj; vb < 100; vb += GBLK) {
        bool pt = (vb < 50);
        int xx = pt ? vb : vb - 50;
        int m0 = xx * 64;
        const ushort* xT  = pt ? p.pfT : p.rgbT;
        const int*    idx = pt ? p.pool_idx : p.r2p_idx;
        int Nin           = pt ? NPTS : HWN;
        const ushort* W   = pt ? wBg : wBg + 4096;   // [64][64]
        const float*  sv  = pt ? p.s_pp : p.s_rp;
        const float*  bv  = pt ? p.b_pp : p.b_rp;
        ushort*       dst = pt ? p.p2rT : p.r2pT;

        int c8   = (tid & 7) * 8;
        int mloc = tid >> 3;          // 0..31: 32 points per pass
        const ushort* xb = xT + (size_t)g * Nin * CC + c8;
        #pragma unroll
        for (int pass = 0; pass < 2; ++pass) {
            int ml = mloc + pass * 32;
            int m  = m0 + ml;
            const int4* ip4 = (const int4*)(idx + ((size_t)g * NSUB + m) * KNN);
            int4 q0 = ip4[0], q1 = ip4[1], q2 = ip4[2], q3 = ip4[3];
            int js[16] = { q0.x, q0.y, q0.z, q0.w, q1.x, q1.y, q1.z, q1.w,
                           q2.x, q2.y, q2.z, q2.w, q3.x, q3.y, q3.z, q3.w };
            float a[8];
            #pragma unroll
            for (int u = 0; u < 8; ++u) a[u] = -1e30f;
            #pragma unroll
            for (int k = 0; k < KNN; ++k) {
                short8 val = *(const short8*)(xb + (size_t)js[k] * CC);
                #pragma unroll
                for (int u = 0; u < 8; ++u)
                    a[u] = fmaxf(a[u], bf2f((unsigned short)val[u]));
            }
            short8 r;
            #pragma unroll
            for (int u = 0; u < 8; ++u) r[u] = (short)f2bf(a[u]);
            *(short8*)(&sg[ml * 72 + c8]) = r;
            if (pt)
                *(short8*)(p.pe0T + ((size_t)g * NSUB + m) * CC + c8) = r;
        }
        __syncthreads();
        int wave = tid >> 6, lane = tid & 63;
        int l15 = lane & 15, quad = lane >> 4;
        int nloc0 = wave * 16;
        floatx4 acc[4] = {{0.f,0.f,0.f,0.f},{0.f,0.f,0.f,0.f},{0.f,0.f,0.f,0.f},{0.f,0.f,0.f,0.f}};
        #pragma unroll
        for (int kk = 0; kk < 2; ++kk) {
            short8 a = *(const short8*)(&sg[(nloc0 + l15) * 72 + kk * 32 + quad * 8]);
            #pragma unroll
            for (int t = 0; t < 4; ++t) {
                short8 wf = *(const short8*)(W + (size_t)(t * 16 + l15) * CC + kk * 32 + quad * 8);
                acc[t] = __builtin_amdgcn_mfma_f32_16x16x32_bf16(a, wf, acc[t], 0, 0, 0);
            }
        }
        #pragma unroll
        for (int t = 0; t < 4; ++t) {
            int o = t * 16 + l15;
            float ss = sv[o], bb2 = bv[o];
            #pragma unroll
            for (int r = 0; r < 4; ++r) {
                int n = m0 + nloc0 + quad * 4 + r;
                float y = fmaxf(acc[t][r] * ss + bb2, 0.f);
                dst[((size_t)g * NSUB + n) * CC + o] = f2bf(y);
            }
        }
        __syncthreads();   // protect sg reuse across grid-stride iterations
    }
    gbar(p.bar, g, lj, 2u);

    // ---- PHASE 3: both fuse GEMMs -> d_out (batch g), 88 vblocks -----------
    for (int vb = lj; vb < 88; vb += GBLK) {
        bool rp = (vb < 75);
        int x0 = rp ? vb : vb - 75;       // rgb 0..74 / pt 0..12
        const ushort* x1T = rp ? p.rgbT : p.pe0T;
        const ushort* x2T = rp ? p.p2rT : p.r2pT;
        int N             = rp ? HWN : NSUB;
        int pos0          = rp ? 0 : HWN;
        const ushort* W   = rp ? wBg + 8192 : wBg + 16384;   // [64][128]
        const float*  sv  = rp ? p.s_pf : p.s_rf;
        const float*  bv  = rp ? p.b_pf : p.b_rf;

        int wave = tid >> 6, lane = tid & 63;
        int l15 = lane & 15, quad = lane >> 4;
        int n_base = x0 * 256 + wave * 64;
        int ncol   = n_base + l15 * 4;
        bool act   = rp || (ncol < NSUB);
        int nc     = act ? ncol : 0;

        // preload all B-fragments: xf[kk][gg], 16 independent 16B loads
        short8 xf[4][4];
        {
            const ushort* r1[4];
            const ushort* r2[4];
            if (rp) {
                int4 i4 = *(const int4*)(p.p2r_idx + (size_t)g * N + nc);
                int n2s[4] = { i4.x, i4.y, i4.z, i4.w };
                #pragma unroll
                for (int gg = 0; gg < 4; ++gg) {
                    r1[gg] = x1T + ((size_t)g * N + nc + gg) * CC + quad * 8;
                    r2[gg] = x2T + ((size_t)g * NSUB + n2s[gg]) * CC + quad * 8;
                }
            } else {
                #pragma unroll
                for (int gg = 0; gg < 4; ++gg) {
                    r1[gg] = x1T + ((size_t)g * N + nc + gg) * CC + quad * 8;
                    r2[gg] = x2T + ((size_t)g * NSUB + nc + gg) * CC + quad * 8;
                }
            }
            #pragma unroll
            for (int gg = 0; gg < 4; ++gg) {
                xf[0][gg] = *(const short8*)(r1[gg]);
                xf[1][gg] = *(const short8*)(r1[gg] + 32);
                xf[2][gg] = *(const short8*)(r2[gg]);
                xf[3][gg] = *(const short8*)(r2[gg] + 32);
            }
        }

        float* outb = p.out + (size_t)g * CC * OUTN + pos0 + nc;
        #pragma unroll
        for (int t = 0; t < 4; ++t) {
            floatx4 acc[4] = {{0.f,0.f,0.f,0.f},{0.f,0.f,0.f,0.f},
                              {0.f,0.f,0.f,0.f},{0.f,0.f,0.f,0.f}};
            #pragma unroll
            for (int kk = 0; kk < 4; ++kk) {
                short8 wf = *(const short8*)(W + (size_t)(t * 16 + l15) * 128 + kk * 32 + quad * 8);
                #pragma unroll
                for (int gg = 0; gg < 4; ++gg)
                    acc[gg] = __builtin_amdgcn_mfma_f32_16x16x32_bf16(wf, xf[kk][gg], acc[gg], 0, 0, 0);
            }
            // store tile t immediately: overlaps next tile's MFMA
            #pragma unroll
            for (int r = 0; r < 4; ++r) {
                int o = t * 16 + quad * 4 + r;
                float ss = sv[o], bb2 = bv[o];
                floatx4 y;
                y[0] = fmaxf(acc[0][r] * ss + bb2, 0.f);
                y[1] = fmaxf(acc[1][r] * ss + bb2, 0.f);
                y[2] = fmaxf(acc[2][r] * ss + bb2, 0.f);
                y[3] = fmaxf(acc[3][r] * ss + bb2, 0.f);
                if (act)
                    __builtin_nontemporal_store(y, (floatx4*)(outb + (size_t)o * OUTN));
            }
        }
    }
}

extern "C" void kernel_launch(void* const* d_in, const int* in_sizes, int n_in,
                              void* d_out, int out_size, void* d_ws, size_t ws_size,
                              hipStream_t stream) {
    char* ws = (char*)d_ws;
    ushort* wB   = (ushort*)ws; ws += (size_t)NGRP * 24576 * 2;   // 8 group copies
    ushort* pfT  = (ushort*)ws; ws += (size_t)BB * NPTS * CC * 2;
    ushort* rgbT = (ushort*)ws; ws += (size_t)BB * HWN  * CC * 2;
    ushort* pe0T = (ushort*)ws; ws += (size_t)BB * NSUB * CC * 2;
    ushort* p2rT = (ushort*)ws; ws += (size_t)BB * NSUB * CC * 2;
    ushort* r2pT = (ushort*)ws; ws += (size_t)BB * NSUB * CC * 2;
    unsigned* bar = (unsigned*)ws; ws += 131072;

    // re-arm barriers every iteration (workspace is poisoned between runs):
    // gens 512B + 960 flags * 64B = 61952B -> memset that much
    hipMemsetAsync(bar, 0, 61952, stream);

    P p;
    p.pfeat = (const float*)d_in[1];
    p.rgb   = (const float*)d_in[0];
    p.w0    = (const float*)d_in[2];
    p.w1    = (const float*)d_in[8];
    p.w2    = (const float*)d_in[5];
    p.w3    = (const float*)d_in[11];
    p.s_pp  = (const float*)d_in[3];   p.b_pp = (const float*)d_in[4];
    p.s_rp  = (const float*)d_in[9];   p.b_rp = (const float*)d_in[10];
    p.s_pf  = (const float*)d_in[6];   p.b_pf = (const float*)d_in[7];
    p.s_rf  = (const float*)d_in[12];  p.b_rf = (const float*)d_in[13];
    p.pool_idx = (const int*)d_in[14];
    p.p2r_idx  = (const int*)d_in[15];
    p.r2p_idx  = (const int*)d_in[16];
    p.wB = wB; p.pfT = pfT; p.rgbT = rgbT;
    p.pe0T = pe0T; p.p2rT = p2rT; p.r2pT = r2pT;
    p.bar = bar;
    p.out = (float*)d_out;

    k_all<<<dim3(GRID_BLOCKS), 256, 0, stream>>>(p);
}

// Round 9
// 168.750 us; speedup vs baseline: 2.0709x; 1.7661x over previous
//
#include <hip/hip_runtime.h>

#define BB   8
#define CC   64
#define HWN  19200
#define NPTS 12800
#define NSUB 3200
#define KNN  16
#define OUTN (HWN + NSUB)   // 22400

typedef __attribute__((ext_vector_type(8))) short short8;
typedef __attribute__((ext_vector_type(4))) float floatx4;

__device__ __forceinline__ unsigned short f2bf(float f) {
    union { float f; unsigned int i; } v; v.f = f;
    unsigned int r = v.i + 0x7fffu + ((v.i >> 16) & 1u);
    return (unsigned short)(r >> 16);
}
__device__ __forceinline__ float bf2f(unsigned short u) {
    union { unsigned int i; float f; } v; v.i = ((unsigned int)u) << 16; return v.f;
}

struct P {
    const float* pfeat; const float* rgb;
    const float* w0; const float* w1; const float* w2; const float* w3;
    const float* s_pp; const float* b_pp;
    const float* s_rp; const float* b_rp;
    const float* s_pf; const float* b_pf;
    const float* s_rf; const float* b_rf;
    const int* pool_idx; const int* p2r_idx; const int* r2p_idx;
    ushort* wB; ushort* pfT; ushort* rgbT;
    ushort* pe0T; ushort* p2rT; ushort* r2pT;
    float* out;
};

// ---------------------------------------------------------------------------
// K1 (reworked R9): transpose f32 [B][C][N] -> bf16 [B][N][C], 128 n/block.
// DIRECT register transpose, no LDS, no __syncthreads: each thread owns an
// 8-channel x 4-n tile. Loads: 8x float4, per-instruction 8 rows x 512B
// contiguous (coalesced). Stores: 4x short8; per instruction 8x128B chunks.
// Replaces 64 scalar LDS ops/thread of the old LDS transpose.
// Session laws: any VGPR spill is catastrophic (R5/R8: spills = 1.5-2x slower)
// -> plain __launch_bounds__(256), natural allocation (~60 VGPR here).
// Fused persistent-kernel variants (R2-R8) all lose to 3 dispatches: separate
// dispatches get full oversubscription; residency-capped spin-barrier can't.
// ---------------------------------------------------------------------------
__global__ __launch_bounds__(256) void k_p1(P p) {
    int w = blockIdx.x, tid = threadIdx.x;
    if (w >= 2000) {
        int i = (w - 2000) * 256 + tid;
        float v;
        if (i < 4096)       v = p.w0[i];
        else if (i < 8192)  v = p.w1[i - 4096];
        else if (i < 16384) v = p.w2[i - 8192];
        else                v = p.w3[i - 16384];
        p.wB[i] = f2bf(v);
        return;
    }
    bool isR = (w >= 800);
    int v0 = isR ? w - 800 : w;
    int b = v0 & 7, xx = v0 >> 3;
    const float* src = (isR ? p.rgb : p.pfeat);
    ushort* outp     = (isR ? p.rgbT : p.pfT);
    int N  = isR ? HWN : NPTS;
    int n0 = xx * 128;
    src += (size_t)b * CC * N + n0;

    int c8 = (tid & 7) * 8;       // channel group 0..56
    int n4 = (tid >> 3) * 4;      // local n 0..124

    float4 v[8];
    #pragma unroll
    for (int u = 0; u < 8; ++u)
        v[u] = *(const float4*)(src + (size_t)(c8 + u) * N + n4);

    ushort* dst = outp + ((size_t)b * N + n0 + n4) * CC + c8;
    #pragma unroll
    for (int i = 0; i < 4; ++i) {
        float vi[8] = { v[0].x, v[0].y, v[0].z, v[0].w,
                        v[4].x, v[4].y, v[4].z, v[4].w };
        // select component i of each of the 8 channel rows
        short8 r;
        r[0] = (short)f2bf(i == 0 ? v[0].x : i == 1 ? v[0].y : i == 2 ? v[0].z : v[0].w);
        r[1] = (short)f2bf(i == 0 ? v[1].x : i == 1 ? v[1].y : i == 2 ? v[1].z : v[1].w);
        r[2] = (short)f2bf(i == 0 ? v[2].x : i == 1 ? v[2].y : i == 2 ? v[2].z : v[2].w);
        r[3] = (short)f2bf(i == 0 ? v[3].x : i == 1 ? v[3].y : i == 2 ? v[3].z : v[3].w);
        r[4] = (short)f2bf(i == 0 ? v[4].x : i == 1 ? v[4].y : i == 2 ? v[4].z : v[4].w);
        r[5] = (short)f2bf(i == 0 ? v[5].x : i == 1 ? v[5].y : i == 2 ? v[5].z : v[5].w);
        r[6] = (short)f2bf(i == 0 ? v[6].x : i == 1 ? v[6].y : i == 2 ? v[6].z : v[6].w);
        r[7] = (short)f2bf(i == 0 ? v[7].x : i == 1 ? v[7].y : i == 2 ? v[7].z : v[7].w);
        (void)vi;
        *(short8*)(dst + (size_t)i * CC) = r;
    }
}

// ---------------------------------------------------------------------------
// K2 (frozen, R0): gather + maxpool + pre-conv GEMM. grid 800.
// ---------------------------------------------------------------------------
__global__ __launch_bounds__(256) void k_p2(P p) {
    __shared__ ushort sm[64 * 72];
    int w = blockIdx.x, tid = threadIdx.x;
    bool pt = (w < 400);
    int v0 = pt ? w : w - 400;
    int b = v0 & 7, xx = v0 >> 3;
    int m0 = xx * 64;
    const ushort* xT  = pt ? p.pfT : p.rgbT;
    const int*    idx = pt ? p.pool_idx : p.r2p_idx;
    int Nin           = pt ? NPTS : HWN;
    const ushort* W   = pt ? p.wB : p.wB + 4096;   // [64][64]
    const float*  sv  = pt ? p.s_pp : p.s_rp;
    const float*  bv  = pt ? p.b_pp : p.b_rp;
    ushort*       dst = pt ? p.p2rT : p.r2pT;

    int c8   = (tid & 7) * 8;
    int mloc = tid >> 3;          // 0..31: 32 points per pass
    const ushort* xb = xT + (size_t)b * Nin * CC + c8;
    #pragma unroll
    for (int pass = 0; pass < 2; ++pass) {
        int ml = mloc + pass * 32;
        int m  = m0 + ml;
        const int4* ip4 = (const int4*)(idx + ((size_t)b * NSUB + m) * KNN);
        int4 q0 = ip4[0], q1 = ip4[1], q2 = ip4[2], q3 = ip4[3];
        int js[16] = { q0.x, q0.y, q0.z, q0.w, q1.x, q1.y, q1.z, q1.w,
                       q2.x, q2.y, q2.z, q2.w, q3.x, q3.y, q3.z, q3.w };
        float a[8];
        #pragma unroll
        for (int u = 0; u < 8; ++u) a[u] = -1e30f;
        #pragma unroll
        for (int k = 0; k < KNN; ++k) {
            short8 val = *(const short8*)(xb + (size_t)js[k] * CC);
            #pragma unroll
            for (int u = 0; u < 8; ++u)
                a[u] = fmaxf(a[u], bf2f((unsigned short)val[u]));
        }
        short8 r;
        #pragma unroll
        for (int u = 0; u < 8; ++u) r[u] = (short)f2bf(a[u]);
        *(short8*)(&sm[ml * 72 + c8]) = r;
        if (pt)
            *(short8*)(p.pe0T + ((size_t)b * NSUB + m) * CC + c8) = r;
    }
    __syncthreads();
    int wave = tid >> 6, lane = tid & 63;
    int l15 = lane & 15, quad = lane >> 4;
    int nloc0 = wave * 16;
    floatx4 acc[4] = {{0.f,0.f,0.f,0.f},{0.f,0.f,0.f,0.f},{0.f,0.f,0.f,0.f},{0.f,0.f,0.f,0.f}};
    #pragma unroll
    for (int kk = 0; kk < 2; ++kk) {
        short8 a = *(const short8*)(&sm[(nloc0 + l15) * 72 + kk * 32 + quad * 8]);
        #pragma unroll
        for (int t = 0; t < 4; ++t) {
            short8 wf = *(const short8*)(W + (size_t)(t * 16 + l15) * CC + kk * 32 + quad * 8);
            acc[t] = __builtin_amdgcn_mfma_f32_16x16x32_bf16(a, wf, acc[t], 0, 0, 0);
        }
    }
    #pragma unroll
    for (int t = 0; t < 4; ++t) {
        int o = t * 16 + l15;
        float ss = sv[o], bb2 = bv[o];
        #pragma unroll
        for (int r = 0; r < 4; ++r) {
            int n = m0 + nloc0 + quad * 4 + r;
            float y = fmaxf(acc[t][r] * ss + bb2, 0.f);
            dst[((size_t)b * NSUB + n) * CC + o] = f2bf(y);
        }
    }
}

// ---------------------------------------------------------------------------
// K3 (frozen, R0): both fuse GEMMs -> d_out. grid 704.
// ---------------------------------------------------------------------------
__global__ __launch_bounds__(256) void k_p3(P p) {
    int w = blockIdx.x, tid = threadIdx.x;
    bool rp = (w < 600);
    int v0 = rp ? w : w - 600;
    int b = v0 & 7, x0 = v0 >> 3;     // rgb 0..74 / pt 0..12
    const ushort* x1T = rp ? p.rgbT : p.pe0T;
    const ushort* x2T = rp ? p.p2rT : p.r2pT;
    int N             = rp ? HWN : NSUB;
    int pos0          = rp ? 0 : HWN;
    const ushort* W   = rp ? p.wB + 8192 : p.wB + 16384;   // [64][128]
    const float*  sv  = rp ? p.s_pf : p.s_rf;
    const float*  bv  = rp ? p.b_pf : p.b_rf;

    int wave = tid >> 6, lane = tid & 63;
    int l15 = lane & 15, quad = lane >> 4;
    int n_base = x0 * 256 + wave * 64;
    int ncol   = n_base + l15 * 4;
    bool act   = rp || (ncol < NSUB);
    int nc     = act ? ncol : 0;

    // preload all B-fragments: xf[kk][g], 16 independent 16B loads
    short8 xf[4][4];
    {
        const ushort* r1[4];
        const ushort* r2[4];
        if (rp) {
            int4 i4 = *(const int4*)(p.p2r_idx + (size_t)b * N + nc);
            int n2s[4] = { i4.x, i4.y, i4.z, i4.w };
            #pragma unroll
            for (int g = 0; g < 4; ++g) {
                r1[g] = x1T + ((size_t)b * N + nc + g) * CC + quad * 8;
                r2[g] = x2T + ((size_t)b * NSUB + n2s[g]) * CC + quad * 8;
            }
        } else {
            #pragma unroll
            for (int g = 0; g < 4; ++g) {
                r1[g] = x1T + ((size_t)b * N + nc + g) * CC + quad * 8;
                r2[g] = x2T + ((size_t)b * NSUB + nc + g) * CC + quad * 8;
            }
        }
        #pragma unroll
        for (int g = 0; g < 4; ++g) {
            xf[0][g] = *(const short8*)(r1[g]);
            xf[1][g] = *(const short8*)(r1[g] + 32);
            xf[2][g] = *(const short8*)(r2[g]);
            xf[3][g] = *(const short8*)(r2[g] + 32);
        }
    }

    float* outb = p.out + (size_t)b * CC * OUTN + pos0 + nc;
    #pragma unroll
    for (int t = 0; t < 4; ++t) {
        floatx4 acc[4] = {{0.f,0.f,0.f,0.f},{0.f,0.f,0.f,0.f},
                          {0.f,0.f,0.f,0.f},{0.f,0.f,0.f,0.f}};
        #pragma unroll
        for (int kk = 0; kk < 4; ++kk) {
            short8 wf = *(const short8*)(W + (size_t)(t * 16 + l15) * 128 + kk * 32 + quad * 8);
            #pragma unroll
            for (int g = 0; g < 4; ++g)
                acc[g] = __builtin_amdgcn_mfma_f32_16x16x32_bf16(wf, xf[kk][g], acc[g], 0, 0, 0);
        }
        // store tile t immediately: overlaps next tile's MFMA
        #pragma unroll
        for (int r = 0; r < 4; ++r) {
            int o = t * 16 + quad * 4 + r;
            float ss = sv[o], bb2 = bv[o];
            floatx4 y;
            y[0] = fmaxf(acc[0][r] * ss + bb2, 0.f);
            y[1] = fmaxf(acc[1][r] * ss + bb2, 0.f);
            y[2] = fmaxf(acc[2][r] * ss + bb2, 0.f);
            y[3] = fmaxf(acc[3][r] * ss + bb2, 0.f);
            if (act)
                __builtin_nontemporal_store(y, (floatx4*)(outb + (size_t)o * OUTN));
        }
    }
}

extern "C" void kernel_launch(void* const* d_in, const int* in_sizes, int n_in,
                              void* d_out, int out_size, void* d_ws, size_t ws_size,
                              hipStream_t stream) {
    char* ws = (char*)d_ws;
    ushort* wB   = (ushort*)ws; ws += 24576 * 2;
    ushort* pfT  = (ushort*)ws; ws += (size_t)BB * NPTS * CC * 2;
    ushort* rgbT = (ushort*)ws; ws += (size_t)BB * HWN  * CC * 2;
    ushort* pe0T = (ushort*)ws; ws += (size_t)BB * NSUB * CC * 2;
    ushort* p2rT = (ushort*)ws; ws += (size_t)BB * NSUB * CC * 2;
    ushort* r2pT = (ushort*)ws; ws += (size_t)BB * NSUB * CC * 2;

    P p;
    p.pfeat = (const float*)d_in[1];
    p.rgb   = (const float*)d_in[0];
    p.w0    = (const float*)d_in[2];
    p.w1    = (const float*)d_in[8];
    p.w2    = (const float*)d_in[5];
    p.w3    = (const float*)d_in[11];
    p.s_pp  = (const float*)d_in[3];   p.b_pp = (const float*)d_in[4];
    p.s_rp  = (const float*)d_in[9];   p.b_rp = (const float*)d_in[10];
    p.s_pf  = (const float*)d_in[6];   p.b_pf = (const float*)d_in[7];
    p.s_rf  = (const float*)d_in[12];  p.b_rf = (const float*)d_in[13];
    p.pool_idx = (const int*)d_in[14];
    p.p2r_idx  = (const int*)d_in[15];
    p.r2p_idx  = (const int*)d_in[16];
    p.wB = wB; p.pfT = pfT; p.rgbT = rgbT;
    p.pe0T = pe0T; p.p2rT = p2rT; p.r2pT = r2pT;
    p.out = (float*)d_out;

    k_p1<<<dim3(2096), 256, 0, stream>>>(p);
    k_p2<<<dim3(800),  256, 0, stream>>>(p);
    k_p3<<<dim3(704),  256, 0, stream>>>(p);
}